// Round 4
// baseline (188.254 us; speedup 1.0000x reference)
//
#include <hip/hip_runtime.h>
#include <stdint.h>

// Problem constants
#define B_    8
#define CIN   512
#define NPIX  16384
#define CK    256
#define KCTX  64
#define CV    256

typedef _Float16 f16;
typedef _Float16 f16x4 __attribute__((ext_vector_type(4)));
typedef _Float16 f16x8 __attribute__((ext_vector_type(8)));
typedef float    f32x4 __attribute__((ext_vector_type(4)));

#define LOG2E 1.44269504f

// ws layout (bytes), total 1.5 MB
#define WQKT_OFF 0          // 512 KB : Wqk^T*scale f16 swz [b][c-chunk 8][64m rows of 128B]
#define WPV_OFF  524288     // 512 KB : Wpv f16 frag-order  [b][512c rows of 128B]
#define KF_OFF   1048576    // 256 KB : k  f16 [b][256 kk][64 m]
#define VM_OFF   1310720    // 256 KB : vm f16 [b][256 v ][64 m]

__device__ __forceinline__ void gl_lds16(const void* g, void* l) {
    __builtin_amdgcn_global_load_lds(
        (const __attribute__((address_space(1))) uint32_t*)g,
        (__attribute__((address_space(3))) uint32_t*)l, 16, 0, 0);
}

// ---------------------------------------------------------------------------
// prep1: k[row][m] = sum_c Wk[row][c]*ctx[b][c][m];  vm[row][m] = same with Wv
// ---------------------------------------------------------------------------
__global__ __launch_bounds__(1024) void prep1(const float* __restrict__ ctx,
                                              const float* __restrict__ Wk,
                                              const float* __restrict__ Wv,
                                              char* __restrict__ ws) {
    const int p = blockIdx.x;
    const int b = blockIdx.y;
    const int t = threadIdx.x;
    const int m = t & 63;
    const int rg = t >> 6;
    const int row = (p & 15) * 16 + rg;
    const bool is_k = (p < 16);
    const float* W = (is_k ? Wk : Wv) + (size_t)row * CV;
    const float* cb = ctx + (size_t)b * CV * KCTX + m;
    float acc = 0.f;
    #pragma unroll 8
    for (int c = 0; c < CV; ++c)
        acc = fmaf(W[c], cb[(size_t)c * KCTX], acc);
    char* dst = ws + (is_k ? KF_OFF : VM_OFF) + b * 32768 + (row * 64 + m) * 2;
    *(f16*)dst = (f16)acc;
}

// ---------------------------------------------------------------------------
// prep2: Wqk[c][m] = sum_kk Wq[kk][c]*k[kk][m]  (store *1/16, chunked swizzled)
//        Wpv[c][m] = sum_v  Wp[c][v]*vm[v][m]   (store in MFMA-B fragment order)
// Wpv byte(c,m): slot=(m>>5)*4+((m>>2)&3), j=((m>>4)&1)*4+(m&3)
//                byte = c*128 + 16*(slot ^ (c&7)) + 2*j
// ---------------------------------------------------------------------------
__global__ __launch_bounds__(1024) void prep2(const float* __restrict__ Wq,
                                              const float* __restrict__ Wp,
                                              char* __restrict__ ws) {
    const int p = blockIdx.x;
    const int b = blockIdx.y;
    const int t = threadIdx.x;
    const int m = t & 63;
    const int cg = t >> 6;
    float acc[4] = {0.f, 0.f, 0.f, 0.f};
    if (p < 8) {
        const int cb = p * 64 + cg * 4;
        const f16* kf = (const f16*)(ws + KF_OFF + b * 32768) + m;
        for (int kk = 0; kk < CK; ++kk) {
            f32x4 wv = *(const f32x4*)(Wq + (size_t)kk * CIN + cb);
            float kv = (float)kf[kk * 64];
            #pragma unroll
            for (int i = 0; i < 4; ++i) acc[i] = fmaf(wv[i], kv, acc[i]);
        }
        char* base = ws + WQKT_OFF + b * 65536;
        #pragma unroll
        for (int i = 0; i < 4; ++i) {
            int c = cb + i;
            int byte = (c >> 6) * 8192 + m * 128 + 16 * (((c >> 3) & 7) ^ (m & 7)) + 2 * (c & 7);
            *(f16*)(base + byte) = (f16)(acc[i] * 0.0625f);   // fold scale 1/16
        }
    } else {
        const int cb = (p - 8) * 64 + cg * 4;
        const f16* vm = (const f16*)(ws + VM_OFF + b * 32768) + m;
        for (int v = 0; v < CV; v += 4) {
            f32x4 wp[4];
            #pragma unroll
            for (int i = 0; i < 4; ++i)
                wp[i] = *(const f32x4*)(Wp + (size_t)(cb + i) * CV + v);
            #pragma unroll
            for (int j = 0; j < 4; ++j) {
                float vv = (float)vm[(v + j) * 64];
                #pragma unroll
                for (int i = 0; i < 4; ++i) acc[i] = fmaf(wp[i][j], vv, acc[i]);
            }
        }
        char* base = ws + WPV_OFF + b * 65536;
        const int slot = (m >> 5) * 4 + ((m >> 2) & 3);
        const int jj   = ((m >> 4) & 1) * 4 + (m & 3);
        #pragma unroll
        for (int i = 0; i < 4; ++i) {
            int c = cb + i;
            *(f16*)(base + c * 128 + 16 * (slot ^ (c & 7)) + 2 * jj) = (f16)acc[i];
        }
    }
}

// ---------------------------------------------------------------------------
// fused: per (batch, 128-pixel tile), 512 threads = 8 waves.
//   sim_T[m][n] = sum_c Wqk_s[c][m] * x[c][n]    (8 K-chunks of 64)
//   attn = softmax_m, fully in-register
//   out[c][n]   = attn (reg A-frag) x Wpv (LDS)  -> f32x4 stores, D=[n][c]
// LDS 64 KB: sim uses x_s 2x16K + wq_s 2x8K; out phase reuses all 64K for Wpv.
// ---------------------------------------------------------------------------
__global__ __launch_bounds__(512, 4) void fused(const float* __restrict__ x,
                                                const char* __restrict__ ws,
                                                float* __restrict__ out) {
    __shared__ char lds[65536];
    char* x_s  = lds;            // [128 n][64 c] f16 swz, double-buffered
    char* wq_s = lds + 32768;    // [64 m][64 c] f16 swz, double-buffered

    const int b  = blockIdx.y;
    const int n0 = blockIdx.x * 128;
    const int t  = threadIdx.x;
    const int w  = t >> 6, l = t & 63, g = l >> 4, ln = l & 15;
    const int nB = 16 * w + ln;
    const int fnB = (nB ^ (nB >> 3)) & 7;

    const float* xb = x + (size_t)b * CIN * NPIX + n0;
    const char* wqkt_g = ws + WQKT_OFF + b * 65536;
    const char* wpv_g  = ws + WPV_OFF  + b * 65536;

    const int n4 = (t & 31) * 4;           // 4 consecutive n staged per thread
    const int c4 = (t >> 5) * 4;           // 4 consecutive c rows per thread
    const int cslot = (c4 >> 3) & 7;
    const int coff  = 2 * (c4 & 7);

    // ---- prologue: chunk 0 ----
    gl_lds16(wqkt_g + t * 16, wq_s + t * 16);
    f32x4 xr[4];
    {
        const float* xp = xb + (size_t)c4 * NPIX + n4;
        #pragma unroll
        for (int i = 0; i < 4; ++i)
            xr[i] = __builtin_nontemporal_load((const f32x4*)(xp + (size_t)i * NPIX));
    }
    #pragma unroll
    for (int j = 0; j < 4; ++j) {
        f16x4 v4; v4[0] = (f16)xr[0][j]; v4[1] = (f16)xr[1][j]; v4[2] = (f16)xr[2][j]; v4[3] = (f16)xr[3][j];
        int n = n4 + j;
        int fn = (n ^ (n >> 3)) & 7;
        *(f16x4*)(x_s + n * 128 + 16 * (cslot ^ fn) + coff) = v4;
    }
    __syncthreads();

    // ---- sim: 8 K-chunks of 64 c ----
    f32x4 accs[4] = {};
    for (int s = 0; s < 8; ++s) {
        const char* xc = x_s + (s & 1) * 16384;
        const char* wc = wq_s + (s & 1) * 8192;
        if (s < 7) {
            gl_lds16(wqkt_g + (s + 1) * 8192 + t * 16, wq_s + ((s + 1) & 1) * 8192 + t * 16);
            const float* xp = xb + (size_t)((s + 1) * 64 + c4) * NPIX + n4;
            #pragma unroll
            for (int i = 0; i < 4; ++i)
                xr[i] = __builtin_nontemporal_load((const f32x4*)(xp + (size_t)i * NPIX));
        }
        #pragma unroll
        for (int kk = 0; kk < 2; ++kk) {
            int kb = kk * 4 + g;
            f16x8 bf = *(const f16x8*)(xc + nB * 128 + 16 * (kb ^ fnB));
            #pragma unroll
            for (int mi = 0; mi < 4; ++mi) {
                int mm = 16 * mi + ln;
                f16x8 af = *(const f16x8*)(wc + mm * 128 + 16 * (kb ^ (mm & 7)));
                accs[mi] = __builtin_amdgcn_mfma_f32_16x16x32_f16(af, bf, accs[mi], 0, 0, 0);
            }
        }
        if (s < 7) {
            char* xn = x_s + ((s + 1) & 1) * 16384;
            #pragma unroll
            for (int j = 0; j < 4; ++j) {
                f16x4 v4; v4[0] = (f16)xr[0][j]; v4[1] = (f16)xr[1][j]; v4[2] = (f16)xr[2][j]; v4[3] = (f16)xr[3][j];
                int n = n4 + j;
                int fn = (n ^ (n >> 3)) & 7;
                *(f16x4*)(xn + n * 128 + 16 * (cslot ^ fn) + coff) = v4;
            }
        }
        __syncthreads();
    }

    // ---- stage Wpv (64 KB) over the whole LDS; overlap with softmax ----
    #pragma unroll
    for (int r = 0; r < 8; ++r) {
        int ch = t + 512 * r;
        gl_lds16(wpv_g + ch * 16, lds + ch * 16);
    }

    // ---- softmax over m (64), in-register; lane holds m = 16mi+4g+r ----
    float mx = accs[0][0];
    #pragma unroll
    for (int mi = 0; mi < 4; ++mi)
        #pragma unroll
        for (int r = 0; r < 4; ++r) mx = fmaxf(mx, accs[mi][r]);
    mx = fmaxf(mx, __shfl_xor(mx, 16, 64));
    mx = fmaxf(mx, __shfl_xor(mx, 32, 64));
    float pv[4][4];
    float sum = 0.f;
    #pragma unroll
    for (int mi = 0; mi < 4; ++mi)
        #pragma unroll
        for (int r = 0; r < 4; ++r) {
            float pe = __builtin_amdgcn_exp2f((accs[mi][r] - mx) * LOG2E);
            pv[mi][r] = pe; sum += pe;
        }
    sum += __shfl_xor(sum, 16, 64);
    sum += __shfl_xor(sum, 32, 64);
    float inv = 1.f / sum;

    // attn A-fragments, register-direct: (kk,g,j) -> m = 16*(2kk+(j>>2)) + 4g + (j&3)
    f16x8 afr[2];
    #pragma unroll
    for (int kk = 0; kk < 2; ++kk)
        #pragma unroll
        for (int j = 0; j < 8; ++j)
            afr[kk][j] = (f16)(pv[2 * kk + (j >> 2)][j & 3] * inv);
    __syncthreads();   // Wpv staged

    // ---- out: D[n][c] tiles; lane stores f32x4 of 4 consecutive n ----
    float* ob = out + (size_t)b * CIN * NPIX + n0 + 16 * w + 4 * g;
    #pragma unroll 4
    for (int ct = 0; ct < 32; ++ct) {
        int c = 16 * ct + ln;
        f32x4 acc = {};
        #pragma unroll
        for (int kk = 0; kk < 2; ++kk) {
            f16x8 bf = *(const f16x8*)(lds + c * 128 + 16 * ((kk * 4 + g) ^ (c & 7)));
            acc = __builtin_amdgcn_mfma_f32_16x16x32_f16(afr[kk], bf, acc, 0, 0, 0);
        }
        __builtin_nontemporal_store(acc, (f32x4*)(ob + (size_t)c * NPIX));
    }
}

// ---------------------------------------------------------------------------
extern "C" void kernel_launch(void* const* d_in, const int* in_sizes, int n_in,
                              void* d_out, int out_size, void* d_ws, size_t ws_size,
                              hipStream_t stream) {
    (void)in_sizes; (void)n_in; (void)out_size; (void)ws_size;
    const float* x   = (const float*)d_in[0];
    const float* ctx = (const float*)d_in[1];
    const float* Wq  = (const float*)d_in[2];
    const float* Wk  = (const float*)d_in[3];
    const float* Wv  = (const float*)d_in[4];
    const float* Wp  = (const float*)d_in[5];
    float* out = (float*)d_out;
    char* ws = (char*)d_ws;

    prep1<<<dim3(32, B_), 1024, 0, stream>>>(ctx, Wk, Wv, ws);
    prep2<<<dim3(16, B_), 1024, 0, stream>>>(Wq, Wp, ws);
    fused<<<dim3(NPIX / 128, B_), 512, 0, stream>>>(x, ws, out);
}

// Round 6
// 160.097 us; speedup vs baseline: 1.1759x; 1.1759x over previous
//
#include <hip/hip_runtime.h>
#include <stdint.h>

// Problem constants
#define B_    8
#define CIN   512
#define NPIX  16384
#define CK    256
#define KCTX  64
#define CV    256

typedef _Float16 f16;
typedef _Float16 f16x4 __attribute__((ext_vector_type(4)));
typedef _Float16 f16x8 __attribute__((ext_vector_type(8)));
typedef float    f32x4 __attribute__((ext_vector_type(4)));

#define LOG2E 1.44269504f

// ws layout (bytes), total 1 MB
#define WQKT_OFF 0          // 512 KB : Wqk^T*scale f16 swz [b][c-chunk 8][64m rows of 128B]
#define WPV_OFF  524288     // 512 KB : Wpv f16 frag-order  [b][512c rows of 128B]

#define WAITVM(N) asm volatile("s_waitcnt vmcnt(" #N ")" ::: "memory")
#define LGKM0     asm volatile("s_waitcnt lgkmcnt(0)" ::: "memory")
#define SCHEDB    __builtin_amdgcn_sched_barrier(0)
#define SBAR      __builtin_amdgcn_s_barrier()

__device__ __forceinline__ void gl_lds16(const void* g, void* l) {
    __builtin_amdgcn_global_load_lds(
        (const __attribute__((address_space(1))) uint32_t*)g,
        (__attribute__((address_space(3))) uint32_t*)l, 16, 0, 0);
}

// ---------------------------------------------------------------------------
// prep: grid (4, B), 1024 threads, 64 KB LDS.
//   p>>1==0 (h=p&1): k = Wk*ctx (MFMA) -> LDS; Wqk^T[c][m] for c-half h -> ws
//   p>>1==1 (h=p&1): v = Wv*ctx (MFMA) -> LDS; Wpv[c][m]  for c-half h -> ws
// LDS: ctx_t [64m][256c] f16 swz | kv_s [64m][256row] f16 swz
// ---------------------------------------------------------------------------
__global__ __launch_bounds__(1024) void prep(const float* __restrict__ ctx,
                                             const float* __restrict__ Wk,
                                             const float* __restrict__ Wv,
                                             const float* __restrict__ Wq,
                                             const float* __restrict__ Wp,
                                             char* __restrict__ ws) {
    __shared__ char lds[65536];
    char* ctx_t = lds;              // 32 KB
    char* kv_s  = lds + 32768;      // 32 KB

    const int p = blockIdx.x;
    const int b = blockIdx.y;
    const int path = p >> 1, h = p & 1;
    const int t = threadIdx.x;
    const int w = t >> 6, l = t & 63, g = l >> 4, ln = l & 15;

    // ---- stage ctx transposed: ctx_t[m][c] f16 swz ----
    {
        const int m4 = (t & 15) * 4, c4 = (t >> 4) * 4;
        const float* cp = ctx + (size_t)b * (CV * KCTX) + (size_t)c4 * KCTX + m4;
        f32x4 xr[4];
        #pragma unroll
        for (int i = 0; i < 4; ++i) xr[i] = *(const f32x4*)(cp + (size_t)i * KCTX);
        #pragma unroll
        for (int j = 0; j < 4; ++j) {
            f16x4 v4; v4[0] = (f16)xr[0][j]; v4[1] = (f16)xr[1][j]; v4[2] = (f16)xr[2][j]; v4[3] = (f16)xr[3][j];
            int m = m4 + j;
            *(f16x4*)(ctx_t + m * 512 + 16 * (((c4 >> 3) & 31) ^ (m & 7)) + 2 * (c4 & 7)) = v4;
        }
    }
    __syncthreads();

    // ---- kv GEMM: D[row][m] = (path? Wv : Wk) * ctx, K=256 ----
    {
        const float* W = path ? Wv : Wk;
        const int rbase = 64 * (w >> 2);
        const int mm = 16 * (w & 3) + ln;
        f32x4 acc[4] = {};
        for (int ks = 0; ks < 8; ++ks) {
            f16x8 bf = *(const f16x8*)(ctx_t + mm * 512 + 16 * ((4 * ks + g) ^ (mm & 7)));
            #pragma unroll
            for (int mi = 0; mi < 4; ++mi) {
                int row = rbase + 16 * mi + ln;
                const float* wp0 = W + (size_t)row * CV + 32 * ks + 8 * g;
                f32x4 lo = *(const f32x4*)wp0, hi = *(const f32x4*)(wp0 + 4);
                f16x8 af;
                #pragma unroll
                for (int j = 0; j < 4; ++j) { af[j] = (f16)lo[j]; af[4 + j] = (f16)hi[j]; }
                acc[mi] = __builtin_amdgcn_mfma_f32_16x16x32_f16(af, bf, acc[mi], 0, 0, 0);
            }
        }
        #pragma unroll
        for (int mi = 0; mi < 4; ++mi)
            #pragma unroll
            for (int r = 0; r < 4; ++r) {
                int row = rbase + 16 * mi + 4 * g + r;
                *(f16*)(kv_s + mm * 512 + 16 * ((((row >> 3) & 31)) ^ (mm & 7)) + 2 * (row & 7)) = (f16)acc[mi][r];
            }
    }
    __syncthreads();

    if (path == 0) {
        // ---- Wqk^T[c][m] = sum_kk Wq[kk][c] k[kk][m]; A gathered from global ----
        f32x4 acc2[4] = {};
        const int cA = 256 * h + 16 * w + ln;
        const float* qcol = Wq + cA;
        for (int ks = 0; ks < 8; ++ks) {
            f16x8 af;
            #pragma unroll
            for (int j = 0; j < 8; ++j)
                af[j] = (f16)qcol[(size_t)(32 * ks + 8 * g + j) * CIN];
            #pragma unroll
            for (int ni = 0; ni < 4; ++ni) {
                int m2 = 16 * ni + ln;
                f16x8 bf = *(const f16x8*)(kv_s + m2 * 512 + 16 * ((4 * ks + g) ^ (m2 & 7)));
                acc2[ni] = __builtin_amdgcn_mfma_f32_16x16x32_f16(af, bf, acc2[ni], 0, 0, 0);
            }
        }
        char* dst = ws + WQKT_OFF + b * 65536;
        #pragma unroll
        for (int ni = 0; ni < 4; ++ni)
            #pragma unroll
            for (int r = 0; r < 4; ++r) {
                int c = 256 * h + 16 * w + 4 * g + r, m2 = 16 * ni + ln;
                int byte = (c >> 6) * 8192 + m2 * 128 + 16 * (((c >> 3) & 7) ^ (m2 & 7)) + 2 * (c & 7);
                *(f16*)(dst + byte) = (f16)(acc2[ni][r] * 0.0625f);   // fold scale 1/16
            }
    } else {
        // ---- Wpv[c][m] = sum_v Wp[c][v] v[v][m]; A direct from global ----
        f32x4 acc2[4] = {};
        const int cA = 256 * h + 16 * w + ln;
        for (int ks = 0; ks < 8; ++ks) {
            const float* pp = Wp + (size_t)cA * CV + 32 * ks + 8 * g;
            f32x4 lo = *(const f32x4*)pp, hi = *(const f32x4*)(pp + 4);
            f16x8 af;
            #pragma unroll
            for (int j = 0; j < 4; ++j) { af[j] = (f16)lo[j]; af[4 + j] = (f16)hi[j]; }
            #pragma unroll
            for (int ni = 0; ni < 4; ++ni) {
                int m2 = 16 * ni + ln;
                f16x8 bf = *(const f16x8*)(kv_s + m2 * 512 + 16 * ((4 * ks + g) ^ (m2 & 7)));
                acc2[ni] = __builtin_amdgcn_mfma_f32_16x16x32_f16(af, bf, acc2[ni], 0, 0, 0);
            }
        }
        char* dst = ws + WPV_OFF + b * 65536;
        #pragma unroll
        for (int ni = 0; ni < 4; ++ni)
            #pragma unroll
            for (int r = 0; r < 4; ++r) {
                int c = 256 * h + 16 * w + 4 * g + r, m2 = 16 * ni + ln;
                int slot = (m2 >> 5) * 4 + ((m2 >> 2) & 3), jj = ((m2 >> 4) & 1) * 4 + (m2 & 3);
                *(f16*)(dst + c * 128 + 16 * (slot ^ (c & 7)) + 2 * jj) = (f16)acc2[ni][r];
            }
    }
}

// ---------------------------------------------------------------------------
// fused: per (batch, 128-pixel tile), 512 threads = 8 waves.
// Counted-vmcnt pipeline, 2 barriers/iter:
//   top:  WAITVM(own wq(s)) -> SBAR  (all waves' wq(s) landed)  -> MFMA
//   tail: issue wq(s+1), x(s+2) -> WAITVM(keep 5) -> ds_write x(s+1)
//         -> lgkmcnt(0) -> SBAR
// ---------------------------------------------------------------------------
__global__ __launch_bounds__(512, 4) void fused(const float* __restrict__ x,
                                                const char* __restrict__ ws,
                                                float* __restrict__ out) {
    __shared__ char lds[65536];
    char* x_s  = lds;            // 2 x 16 KB: [128 n][64 c] f16 swz
    char* wq_s = lds + 32768;    // 2 x 8 KB:  [64 m][64 c] f16 swz

    const int b  = blockIdx.y;
    const int n0 = blockIdx.x * 128;
    const int t  = threadIdx.x;
    const int w  = t >> 6, l = t & 63, g = l >> 4, ln = l & 15;
    const int nB = 16 * w + ln;
    const int fnB = (nB ^ (nB >> 3)) & 7;

    const float* xb = x + (size_t)b * CIN * NPIX + n0;
    const char* wqkt_g = ws + WQKT_OFF + b * 65536;
    const char* wpv_g  = ws + WPV_OFF  + b * 65536;

    const int n4 = (t & 31) * 4;
    const int c4 = (t >> 5) * 4;
    const int cslot = (c4 >> 3) & 7;
    const int coff  = 2 * (c4 & 7);

    f32x4 xr[2][4];
    f32x4 accs[4] = {};

    // ---- prologue: wq(0); x(0)->xr0; x(1)->xr1; write x(0); barrier ----
    gl_lds16(wqkt_g + t * 16, wq_s + t * 16);
    SCHEDB;
    {
        const float* xp = xb + (size_t)c4 * NPIX + n4;
        #pragma unroll
        for (int i = 0; i < 4; ++i) xr[0][i] = *(const f32x4*)(xp + (size_t)i * NPIX);
    }
    SCHEDB;
    {
        const float* xp = xb + (size_t)(64 + c4) * NPIX + n4;
        #pragma unroll
        for (int i = 0; i < 4; ++i) xr[1][i] = *(const f32x4*)(xp + (size_t)i * NPIX);
    }
    SCHEDB;
    WAITVM(4);   // retire wq(0)+x(0); x(1) outstanding
    SCHEDB;
    #pragma unroll
    for (int j = 0; j < 4; ++j) {
        f16x4 v4; v4[0] = (f16)xr[0][0][j]; v4[1] = (f16)xr[0][1][j]; v4[2] = (f16)xr[0][2][j]; v4[3] = (f16)xr[0][3][j];
        int n = n4 + j; int fn = (n ^ (n >> 3)) & 7;
        *(f16x4*)(x_s + n * 128 + 16 * (cslot ^ fn) + coff) = v4;
    }
    LGKM0; SCHEDB; SBAR; SCHEDB;   // wq(0) landed for ALL waves; x(0) visible

    // ---- main loop ----
    #pragma unroll
    for (int s = 0; s < 8; ++s) {
        if (s > 0) {
            if (s == 7) { WAITVM(0); } else { WAITVM(4); }   // own wq(s) landed
            SCHEDB; SBAR; SCHEDB;                            // => all waves' wq(s) landed
        }
        {
            const char* xc = x_s + (s & 1) * 16384;
            const char* wc = wq_s + (s & 1) * 8192;
            #pragma unroll
            for (int kk = 0; kk < 2; ++kk) {
                int kb = kk * 4 + g;
                f16x8 bf = *(const f16x8*)(xc + nB * 128 + 16 * (kb ^ fnB));
                #pragma unroll
                for (int mi = 0; mi < 4; ++mi) {
                    int mm = 16 * mi + ln;
                    f16x8 af = *(const f16x8*)(wc + mm * 128 + 16 * (kb ^ (mm & 7)));
                    accs[mi] = __builtin_amdgcn_mfma_f32_16x16x32_f16(af, bf, accs[mi], 0, 0, 0);
                }
            }
        }
        SCHEDB;
        if (s < 7) {   // issue wq(s+1) -> other wq buffer
            gl_lds16(wqkt_g + (s + 1) * 8192 + t * 16, wq_s + ((s + 1) & 1) * 8192 + t * 16);
            SCHEDB;
        }
        if (s < 6) {   // issue x(s+2) -> xr[s&1]
            const float* xp = xb + (size_t)((s + 2) * 64 + c4) * NPIX + n4;
            #pragma unroll
            for (int i = 0; i < 4; ++i) xr[s & 1][i] = *(const f32x4*)(xp + (size_t)i * NPIX);
            SCHEDB;
        }
        if (s < 7) {   // retire x(s+1), write it to xbuf[(s+1)&1]
            if (s < 6) { WAITVM(5); } else { WAITVM(1); }
            SCHEDB;
            char* xn = x_s + ((s + 1) & 1) * 16384;
            #pragma unroll
            for (int j = 0; j < 4; ++j) {
                f16x4 v4;
                v4[0] = (f16)xr[(s + 1) & 1][0][j]; v4[1] = (f16)xr[(s + 1) & 1][1][j];
                v4[2] = (f16)xr[(s + 1) & 1][2][j]; v4[3] = (f16)xr[(s + 1) & 1][3][j];
                int n = n4 + j; int fn = (n ^ (n >> 3)) & 7;
                *(f16x4*)(xn + n * 128 + 16 * (cslot ^ fn) + coff) = v4;
            }
        }
        LGKM0; SCHEDB; SBAR; SCHEDB;   // x(s+1) visible; all reads of bufs done
    }

    // ---- stage Wpv (64 KB over whole LDS); softmax overlaps ----
    #pragma unroll
    for (int r = 0; r < 8; ++r) {
        int ch = t + 512 * r;
        gl_lds16(wpv_g + ch * 16, lds + ch * 16);
    }

    float mx = accs[0][0];
    #pragma unroll
    for (int mi = 0; mi < 4; ++mi)
        #pragma unroll
        for (int r = 0; r < 4; ++r) mx = fmaxf(mx, accs[mi][r]);
    mx = fmaxf(mx, __shfl_xor(mx, 16, 64));
    mx = fmaxf(mx, __shfl_xor(mx, 32, 64));
    float pv[4][4];
    float sum = 0.f;
    #pragma unroll
    for (int mi = 0; mi < 4; ++mi)
        #pragma unroll
        for (int r = 0; r < 4; ++r) {
            float pe = __builtin_amdgcn_exp2f((accs[mi][r] - mx) * LOG2E);
            pv[mi][r] = pe; sum += pe;
        }
    sum += __shfl_xor(sum, 16, 64);
    sum += __shfl_xor(sum, 32, 64);
    float inv = 1.f / sum;

    // attn A-fragments: (kk,g,j) -> m = 16*(2kk+(j>>2)) + 4g + (j&3)
    f16x8 afr[2];
    #pragma unroll
    for (int kk = 0; kk < 2; ++kk)
        #pragma unroll
        for (int j = 0; j < 8; ++j)
            afr[kk][j] = (f16)(pv[2 * kk + (j >> 2)][j & 3] * inv);
    __syncthreads();   // drains vmcnt(0) in every wave + barrier: Wpv staged

    // ---- out: lane stores f32x4 of 4 consecutive n ----
    float* ob = out + (size_t)b * CIN * NPIX + n0 + 16 * w + 4 * g;
    #pragma unroll 4
    for (int ct = 0; ct < 32; ++ct) {
        int c = 16 * ct + ln;
        f32x4 acc = {};
        #pragma unroll
        for (int kk = 0; kk < 2; ++kk) {
            f16x8 bf = *(const f16x8*)(lds + c * 128 + 16 * ((kk * 4 + g) ^ (c & 7)));
            acc = __builtin_amdgcn_mfma_f32_16x16x32_f16(afr[kk], bf, acc, 0, 0, 0);
        }
        *(f32x4*)(ob + (size_t)c * NPIX) = acc;
    }
}

// ---------------------------------------------------------------------------
extern "C" void kernel_launch(void* const* d_in, const int* in_sizes, int n_in,
                              void* d_out, int out_size, void* d_ws, size_t ws_size,
                              hipStream_t stream) {
    (void)in_sizes; (void)n_in; (void)out_size; (void)ws_size;
    const float* x   = (const float*)d_in[0];
    const float* ctx = (const float*)d_in[1];
    const float* Wq  = (const float*)d_in[2];
    const float* Wk  = (const float*)d_in[3];
    const float* Wv  = (const float*)d_in[4];
    const float* Wp  = (const float*)d_in[5];
    float* out = (float*)d_out;
    char* ws = (char*)d_ws;

    prep<<<dim3(4, B_), 1024, 0, stream>>>(ctx, Wk, Wv, Wq, Wp, ws);
    fused<<<dim3(NPIX / 128, B_), 512, 0, stream>>>(x, ws, out);
}